// Round 9
// baseline (1110.665 us; speedup 1.0000x reference)
//
#include <hip/hip_runtime.h>
#include <math.h>

// ---------------- problem constants ----------------
constexpr int B  = 128;
constexpr int N  = 1024;
constexpr int E  = 16384;
constexpr int FIN = 32;
constexpr int H  = 64;
constexpr int K1 = 820, K2 = 656, K3 = 525;
constexpr int NCLS = 10;

// ---------------- CSR build: histogram + scan + scatter (1 block/graph) ----
// Optionally remaps edges through nidx (old-global -> new-global, -1 = drop)
// and writes the remapped edge list back out for the next stage's build.
template<int NPG, bool REMAP, bool HASW>
__global__ __launch_bounds__(1024) void build_kernel(
    const int* __restrict__ src_in, const int* __restrict__ dst_in,
    const int* __restrict__ nidx,  const float* __restrict__ w_in,
    int* __restrict__ esrc_out, int* __restrict__ edst_out,
    int* __restrict__ rowoff, int* __restrict__ csr_src, float* __restrict__ csr_w)
{
    __shared__ int cnt[1024];
    __shared__ int excl[1024];
    const int g = blockIdx.x, tid = threadIdx.x;
    cnt[tid] = 0;
    __syncthreads();
    const size_t gE = (size_t)g * E;
    int sreg[16], dreg[16];
    #pragma unroll
    for (int i = 0; i < 16; ++i) {
        const int e = tid + i * 1024;
        int s = src_in[gE + e], d = dst_in[gE + e];
        if (REMAP) {
            s = (s >= 0) ? nidx[s] : -1;
            d = (d >= 0) ? nidx[d] : -1;
            esrc_out[gE + e] = s;
            edst_out[gE + e] = d;
        }
        if (s < 0 || d < 0) { s = -1; d = -1; }
        sreg[i] = s; dreg[i] = d;
        if (d >= 0) atomicAdd(&cnt[d - g * NPG], 1);
    }
    __syncthreads();
    // exclusive scan over NPG counters (Hillis-Steele on 1024, padded)
    const int v = (tid < NPG) ? cnt[tid] : 0;
    excl[tid] = v;
    __syncthreads();
    int run = v;
    for (int dd = 1; dd < 1024; dd <<= 1) {
        const int t = (tid >= dd) ? excl[tid - dd] : 0;
        __syncthreads();
        run += t;
        excl[tid] = run;
        __syncthreads();
    }
    const int ex = run - v;                    // exclusive prefix
    if (tid < NPG) rowoff[(size_t)g * (NPG + 1) + tid] = ex;
    if (tid == NPG - 1) rowoff[(size_t)g * (NPG + 1) + NPG] = run;
    excl[tid] = ex;
    cnt[tid] = 0;
    __syncthreads();
    #pragma unroll
    for (int i = 0; i < 16; ++i) {
        const int d = dreg[i];
        if (d >= 0) {
            const int dl = d - g * NPG;
            const int pos = excl[dl] + atomicAdd(&cnt[dl], 1);
            csr_src[gE + pos] = sreg[i];
            if (HASW) csr_w[gE + pos] = w_in[gE + tid + i * 1024];
        }
    }
}

// ---------------- CSR gather-aggregate: agg[n] = sum_{e in row(n)} w_e * x[src_e]
// one wave per node (8 nodes/wave), lane = feature; no atomics, no LDS.
template<int KIN, int NPG, bool HASW>
__global__ __launch_bounds__(256) void agg_csr_kernel(
    const float* __restrict__ xin, const int* __restrict__ csr_src,
    const float* __restrict__ csr_w, const int* __restrict__ rowoff,
    float* __restrict__ agg)
{
    const int wave = threadIdx.x >> 6, lane = threadIdx.x & 63;
    const int nbase = (blockIdx.x * 4 + wave) * 8;
    #pragma unroll 2
    for (int rep = 0; rep < 8; ++rep) {
        const int n = nbase + rep;
        const int g = n / NPG, nl = n - g * NPG;
        const size_t gE = (size_t)g * E;
        const int start = rowoff[g * (NPG + 1) + nl];
        const int end   = rowoff[g * (NPG + 1) + nl + 1];
        float acc = 0.f;
        for (int j0 = start; j0 < end; j0 += 64) {
            const int m = end - j0 < 64 ? end - j0 : 64;
            const int idx = j0 + (lane < m ? lane : 0);
            const int ids = csr_src[gE + idx];
            float wch = 1.f;
            if (HASW) wch = csr_w[gE + idx];
            if (KIN == 64) {
                for (int jj = 0; jj < m; ++jj) {
                    const int s = __shfl(ids, jj);
                    if (HASW) {
                        const float w = __shfl(wch, jj);
                        acc = fmaf(w, xin[(size_t)s * KIN + lane], acc);
                    } else {
                        acc += xin[(size_t)s * KIN + lane];
                    }
                }
            } else {  // KIN == 32: two half-waves split the edge list
                const int f = lane & 31, hf = lane >> 5;
                for (int jj = hf; jj < m; jj += 2) {
                    const int s = __shfl(ids, jj);
                    const float w = __shfl(wch, jj);
                    acc = fmaf(w, xin[(size_t)s * KIN + f], acc);
                }
            }
        }
        if (KIN == 32) acc += __shfl_xor(acc, 32);
        if (lane < KIN) agg[(size_t)n * KIN + lane] = acc;
    }
}

// ---------------- fused node linear + relu + pooling score ----------------
// lane = node. 64 accumulators live in registers (o-loop fully unrolled,
// static indexing); inputs streamed once in 8-float chunks; weights are
// wave-uniform -> s_load + SGPR operands. No LDS, no input re-reads.
template<int KIN>
__global__ __launch_bounds__(256, 4) void lin_score_kernel(
    const float* __restrict__ agg, const float* __restrict__ xin,
    const float* __restrict__ wr,  const float* __restrict__ br,
    const float* __restrict__ wk,  const float* __restrict__ pw,
    float* __restrict__ h, float* __restrict__ score)
{
    const int node = blockIdx.x * 256 + threadIdx.x;
    float acc[64];
    #pragma unroll
    for (int o = 0; o < 64; ++o) acc[o] = br[o];

    const float4* ar = (const float4*)(agg + (size_t)node * KIN);
    const float4* xr = (const float4*)(xin + (size_t)node * KIN);
    for (int kb = 0; kb < KIN / 8; ++kb) {
        const float4 a0 = ar[2 * kb], a1 = ar[2 * kb + 1];
        const float4 x0 = xr[2 * kb], x1 = xr[2 * kb + 1];
        const float a[8]  = {a0.x, a0.y, a0.z, a0.w, a1.x, a1.y, a1.z, a1.w};
        const float xv[8] = {x0.x, x0.y, x0.z, x0.w, x1.x, x1.y, x1.z, x1.w};
        const float* wrb = wr + kb * 8;
        const float* wkb = wk + kb * 8;
        #pragma unroll
        for (int o = 0; o < 64; ++o) {
            #pragma unroll
            for (int kk = 0; kk < 8; ++kk) {
                acc[o] = fmaf(a[kk],  wrb[o * KIN + kk], acc[o]);
                acc[o] = fmaf(xv[kk], wkb[o * KIN + kk], acc[o]);
            }
        }
    }

    float nrm2 = 0.f, p = 0.f;
    #pragma unroll
    for (int o = 0; o < 64; ++o) {
        const float pwo = pw[o];
        nrm2 = fmaf(pwo, pwo, nrm2);
        acc[o] = fmaxf(acc[o], 0.f);
        p = fmaf(acc[o], pwo, p);
    }
    float4* hrow = (float4*)(h + (size_t)node * 64);
    #pragma unroll
    for (int og = 0; og < 16; ++og)
        hrow[og] = make_float4(acc[4 * og], acc[4 * og + 1],
                               acc[4 * og + 2], acc[4 * og + 3]);
    score[node] = tanhf(p * rsqrtf(nrm2));
}

// ---------------- per-graph top-k via bitonic sort ----------------
// total order: (score desc, index asc) — matches jax.lax.top_k tie-breaking.
template<int NREAL, int KSEL>
__global__ __launch_bounds__(512) void topk_kernel(
    const float* __restrict__ score, int* __restrict__ sel, int* __restrict__ nidx)
{
    __shared__ float sval[1024];
    __shared__ int   sidx[1024];
    const int g = blockIdx.x, tid = threadIdx.x;
    for (int i = tid; i < 1024; i += 512) {
        sval[i] = (i < NREAL) ? score[(size_t)g * NREAL + i] : -2.0f;
        sidx[i] = i;
    }
    __syncthreads();
    for (int k = 2; k <= 1024; k <<= 1)
        for (int j = k >> 1; j > 0; j >>= 1) {
            for (int i = tid; i < 1024; i += 512) {
                const int l = i ^ j;
                if (l > i) {
                    const float a = sval[i], bv = sval[l];
                    const int   ia = sidx[i], ib = sidx[l];
                    const bool swap_desc = (a < bv) || (a == bv && ia > ib);
                    if (swap_desc == ((i & k) == 0)) {
                        sval[i] = bv; sval[l] = a;
                        sidx[i] = ib; sidx[l] = ia;
                    }
                }
            }
            __syncthreads();
        }
    for (int j = tid; j < NREAL; j += 512) {
        const int node = sidx[j];
        if (j < KSEL) {
            sel[(size_t)g * KSEL + j] = node;
            nidx[(size_t)g * NREAL + node] = g * KSEL + j;
        } else {
            nidx[(size_t)g * NREAL + node] = -1;
        }
    }
}

// ---------------- pooled gather: xg[new] = h[old] * score[old] ----------------
__global__ __launch_bounds__(256) void gather_kernel(
    const float* __restrict__ h, const float* __restrict__ score,
    const int* __restrict__ sel, float* __restrict__ xg, int KSEL, int NPREV)
{
    const size_t i = (size_t)blockIdx.x * 256 + threadIdx.x;
    const int f = (int)(i & 63);
    const size_t n = i >> 6;
    const int g = (int)(n / KSEL);
    const int old = sel[n];
    const size_t oldg = (size_t)g * NPREV + old;
    xg[i] = h[oldg * 64 + f] * score[oldg];
}

// ---------------- readout: concat(max, mean) over k nodes ----------------
__global__ __launch_bounds__(256) void readout_kernel(
    const float* __restrict__ xg, float* __restrict__ out, int KSEL)
{
    const int g = blockIdx.x, tid = threadIdx.x;
    const int f = tid & 63, jc = tid >> 6;
    float mx = -3.4e38f, sm = 0.f;
    #pragma unroll 4
    for (int j = jc; j < KSEL; j += 4) {
        const float v = xg[((size_t)g * KSEL + j) * 64 + f];
        mx = fmaxf(mx, v); sm += v;
    }
    __shared__ float smx[256], ssm[256];
    smx[tid] = mx; ssm[tid] = sm;
    __syncthreads();
    if (tid < 64) {
        mx = fmaxf(fmaxf(smx[tid], smx[tid + 64]), fmaxf(smx[tid + 128], smx[tid + 192]));
        sm = ssm[tid] + ssm[tid + 64] + ssm[tid + 128] + ssm[tid + 192];
        out[g * 128 + tid] = mx;
        out[g * 128 + 64 + tid] = sm / (float)KSEL;
    }
}

// ---------------- final MLP + log_softmax (one wave per graph) ----------------
__global__ __launch_bounds__(64) void mlp_kernel(
    const float* __restrict__ x1, const float* __restrict__ x2, const float* __restrict__ x3,
    const float* __restrict__ w1, const float* __restrict__ b1,
    const float* __restrict__ w2, const float* __restrict__ b2,
    const float* __restrict__ w3, const float* __restrict__ b3,
    const float* __restrict__ w4, const float* __restrict__ b4,
    float* __restrict__ out)
{
    const int g = blockIdx.x, lane = threadIdx.x;
    __shared__ float z[128], a1[64], a2[32], a3[16], y[16], red[2];
    z[lane]      = x1[g * 128 + lane]      + x2[g * 128 + lane]      + x3[g * 128 + lane];
    z[lane + 64] = x1[g * 128 + 64 + lane] + x2[g * 128 + 64 + lane] + x3[g * 128 + 64 + lane];
    __syncthreads();
    float acc = b1[lane];
    #pragma unroll
    for (int k = 0; k < 128; ++k) acc = fmaf(z[k], w1[lane * 128 + k], acc);
    a1[lane] = fmaxf(acc, 0.f);
    __syncthreads();
    if (lane < 32) {
        float a = b2[lane];
        #pragma unroll
        for (int k = 0; k < 64; ++k) a = fmaf(a1[k], w2[lane * 64 + k], a);
        a2[lane] = fmaxf(a, 0.f);
    }
    __syncthreads();
    if (lane < 16) {
        float a = b3[lane];
        #pragma unroll
        for (int k = 0; k < 32; ++k) a = fmaf(a2[k], w3[lane * 32 + k], a);
        a3[lane] = fmaxf(a, 0.f);
    }
    __syncthreads();
    if (lane < NCLS) {
        float a = b4[lane];
        #pragma unroll
        for (int k = 0; k < 16; ++k) a = fmaf(a3[k], w4[lane * 16 + k], a);
        y[lane] = a;
    }
    __syncthreads();
    if (lane == 0) {
        float m = y[0];
        for (int c = 1; c < NCLS; ++c) m = fmaxf(m, y[c]);
        float s = 0.f;
        for (int c = 0; c < NCLS; ++c) s += expf(y[c] - m);
        red[0] = m; red[1] = logf(s);
    }
    __syncthreads();
    if (lane < NCLS) out[g * NCLS + lane] = y[lane] - red[0] - red[1];
}

// ---------------- workspace layout (bytes) ----------------
constexpr size_t OFF_H      = 0;                                     // B*N*64 f32
constexpr size_t OFF_AGG    = OFF_H      + (size_t)B * N * H * 4;
constexpr size_t OFF_XG     = OFF_AGG    + (size_t)B * N * H * 4;    // B*K1*64 f32
constexpr size_t OFF_SCORE  = OFF_XG     + (size_t)B * K1 * H * 4;
constexpr size_t OFF_SEL    = OFF_SCORE  + (size_t)B * N * 4;
constexpr size_t OFF_NIDX   = OFF_SEL    + (size_t)B * K1 * 4;
constexpr size_t OFF_CSRS   = OFF_NIDX   + (size_t)B * N * 4;        // B*E int
constexpr size_t OFF_CSRW   = OFF_CSRS   + (size_t)B * E * 4;        // B*E f32 (stage1) / esrc (stages 2,3)
constexpr size_t OFF_EDST   = OFF_CSRW   + (size_t)B * E * 4;        // B*E int
constexpr size_t OFF_ROW    = OFF_EDST   + (size_t)B * E * 4;        // B*(N+1) int
constexpr size_t OFF_X1     = OFF_ROW    + (size_t)B * (N + 1) * 4;
constexpr size_t OFF_X2     = OFF_X1     + (size_t)B * 128 * 4;
constexpr size_t OFF_X3     = OFF_X2     + (size_t)B * 128 * 4;

extern "C" void kernel_launch(void* const* d_in, const int* in_sizes, int n_in,
                              void* d_out, int out_size, void* d_ws, size_t ws_size,
                              hipStream_t stream)
{
    (void)in_sizes; (void)n_in; (void)out_size; (void)ws_size;
    const float* x     = (const float*)d_in[0];
    const int*   eidx  = (const int*)d_in[1];
    const float* eattr = (const float*)d_in[2];
    const int* src0 = eidx;
    const int* dst0 = eidx + (size_t)B * E;
    const float* c1_wr = (const float*)d_in[3],  *c1_br = (const float*)d_in[4];
    const float* c1_wk = (const float*)d_in[5],  *p1_w  = (const float*)d_in[6];
    const float* c2_wr = (const float*)d_in[7],  *c2_br = (const float*)d_in[8];
    const float* c2_wk = (const float*)d_in[9],  *p2_w  = (const float*)d_in[10];
    const float* c3_wr = (const float*)d_in[11], *c3_br = (const float*)d_in[12];
    const float* c3_wk = (const float*)d_in[13], *p3_w  = (const float*)d_in[14];
    const float* l1_w = (const float*)d_in[15], *l1_b = (const float*)d_in[16];
    const float* l2_w = (const float*)d_in[17], *l2_b = (const float*)d_in[18];
    const float* l3_w = (const float*)d_in[19], *l3_b = (const float*)d_in[20];
    const float* l4_w = (const float*)d_in[21], *l4_b = (const float*)d_in[22];

    char* ws = (char*)d_ws;
    float* h       = (float*)(ws + OFF_H);
    float* agg     = (float*)(ws + OFF_AGG);
    float* xg      = (float*)(ws + OFF_XG);
    float* score   = (float*)(ws + OFF_SCORE);
    int*   sel     = (int*)  (ws + OFF_SEL);
    int*   nidx    = (int*)  (ws + OFF_NIDX);
    int*   csr_src = (int*)  (ws + OFF_CSRS);
    float* csr_w   = (float*)(ws + OFF_CSRW);   // stage 1 weights
    int*   esrc    = (int*)  (ws + OFF_CSRW);   // stages 2/3 remapped src (aliases csr_w)
    int*   edst    = (int*)  (ws + OFF_EDST);
    int*   rowoff  = (int*)  (ws + OFF_ROW);
    float* x1      = (float*)(ws + OFF_X1);
    float* x2      = (float*)(ws + OFF_X2);
    float* x3      = (float*)(ws + OFF_X3);
    float* out     = (float*)d_out;

    // ---- stage 1 ----
    build_kernel<N, false, true><<<B, 1024, 0, stream>>>(
        src0, dst0, nullptr, eattr, nullptr, nullptr, rowoff, csr_src, csr_w);
    agg_csr_kernel<FIN, N, true><<<(B * N) / 32, 256, 0, stream>>>(
        x, csr_src, csr_w, rowoff, agg);
    lin_score_kernel<FIN><<<(B * N) / 256, 256, 0, stream>>>(
        agg, x, c1_wr, c1_br, c1_wk, p1_w, h, score);
    topk_kernel<N, K1><<<B, 512, 0, stream>>>(score, sel, nidx);
    gather_kernel<<<(B * K1 * 64) / 256, 256, 0, stream>>>(h, score, sel, xg, K1, N);
    readout_kernel<<<B, 256, 0, stream>>>(xg, x1, K1);

    // ---- stage 2 ----  (remap stage-1 edges through nidx1, build CSR over K1 nodes)
    build_kernel<K1, true, false><<<B, 1024, 0, stream>>>(
        src0, dst0, nidx, nullptr, esrc, edst, rowoff, csr_src, nullptr);
    agg_csr_kernel<H, K1, false><<<(B * K1) / 32, 256, 0, stream>>>(
        xg, csr_src, nullptr, rowoff, agg);
    lin_score_kernel<H><<<(B * K1) / 256, 256, 0, stream>>>(
        agg, xg, c2_wr, c2_br, c2_wk, p2_w, h, score);
    topk_kernel<K1, K2><<<B, 512, 0, stream>>>(score, sel, nidx);
    gather_kernel<<<(B * K2 * 64) / 256, 256, 0, stream>>>(h, score, sel, xg, K2, K1);
    readout_kernel<<<B, 256, 0, stream>>>(xg, x2, K2);

    // ---- stage 3 ----  (remap stage-2 edges in place through nidx2)
    build_kernel<K2, true, false><<<B, 1024, 0, stream>>>(
        esrc, edst, nidx, nullptr, esrc, edst, rowoff, csr_src, nullptr);
    agg_csr_kernel<H, K2, false><<<(B * K2) / 32, 256, 0, stream>>>(
        xg, csr_src, nullptr, rowoff, agg);
    lin_score_kernel<H><<<(B * K2) / 256, 256, 0, stream>>>(
        agg, xg, c3_wr, c3_br, c3_wk, p3_w, h, score);
    topk_kernel<K2, K3><<<B, 512, 0, stream>>>(score, sel, nidx);
    gather_kernel<<<(B * K3 * 64) / 256, 256, 0, stream>>>(h, score, sel, xg, K3, K2);
    readout_kernel<<<B, 256, 0, stream>>>(xg, x3, K3);

    // ---- head ----
    mlp_kernel<<<B, 64, 0, stream>>>(x1, x2, x3, l1_w, l1_b, l2_w, l2_b,
                                     l3_w, l3_b, l4_w, l4_b, out);
}

// Round 11
// 929.452 us; speedup vs baseline: 1.1950x; 1.1950x over previous
//
#include <hip/hip_runtime.h>
#include <math.h>

// ---------------- problem constants ----------------
constexpr int B  = 128;
constexpr int N  = 1024;
constexpr int E  = 16384;
constexpr int FIN = 32;
constexpr int H  = 64;
constexpr int K1 = 820, K2 = 656, K3 = 525;
constexpr int NCLS = 10;

// ---------------- CSR build: histogram + scan + scatter (1 block/graph) ----
// Optionally remaps edges through nidx (old-global -> new-global, -1 = drop)
// and writes the remapped edge list back out for the next stage's build.
template<int NPG, bool REMAP, bool HASW>
__global__ __launch_bounds__(1024) void build_kernel(
    const int* __restrict__ src_in, const int* __restrict__ dst_in,
    const int* __restrict__ nidx,  const float* __restrict__ w_in,
    int* __restrict__ esrc_out, int* __restrict__ edst_out,
    int* __restrict__ rowoff, int* __restrict__ csr_src, float* __restrict__ csr_w)
{
    __shared__ int cnt[1024];
    __shared__ int excl[1024];
    const int g = blockIdx.x, tid = threadIdx.x;
    cnt[tid] = 0;
    __syncthreads();
    const size_t gE = (size_t)g * E;
    int sreg[16], dreg[16];
    #pragma unroll
    for (int i = 0; i < 16; ++i) {
        const int e = tid + i * 1024;
        int s = src_in[gE + e], d = dst_in[gE + e];
        if (REMAP) {
            s = (s >= 0) ? nidx[s] : -1;
            d = (d >= 0) ? nidx[d] : -1;
            esrc_out[gE + e] = s;
            edst_out[gE + e] = d;
        }
        if (s < 0 || d < 0) { s = -1; d = -1; }
        sreg[i] = s; dreg[i] = d;
        if (d >= 0) atomicAdd(&cnt[d - g * NPG], 1);
    }
    __syncthreads();
    // exclusive scan over NPG counters (Hillis-Steele on 1024, padded)
    const int v = (tid < NPG) ? cnt[tid] : 0;
    excl[tid] = v;
    __syncthreads();
    int run = v;
    for (int dd = 1; dd < 1024; dd <<= 1) {
        const int t = (tid >= dd) ? excl[tid - dd] : 0;
        __syncthreads();
        run += t;
        excl[tid] = run;
        __syncthreads();
    }
    const int ex = run - v;                    // exclusive prefix
    if (tid < NPG) rowoff[(size_t)g * (NPG + 1) + tid] = ex;
    if (tid == NPG - 1) rowoff[(size_t)g * (NPG + 1) + NPG] = run;
    excl[tid] = ex;
    cnt[tid] = 0;
    __syncthreads();
    #pragma unroll
    for (int i = 0; i < 16; ++i) {
        const int d = dreg[i];
        if (d >= 0) {
            const int dl = d - g * NPG;
            const int pos = excl[dl] + atomicAdd(&cnt[dl], 1);
            csr_src[gE + pos] = sreg[i];
            if (HASW) csr_w[gE + pos] = w_in[gE + tid + i * 1024];
        }
    }
}

// ---------------- CSR gather-aggregate: agg[n] = sum_{e in row(n)} w_e * x[src_e]
// one wave per node (8 nodes/wave), lane = feature; no atomics, no LDS.
template<int KIN, int NPG, bool HASW>
__global__ __launch_bounds__(256) void agg_csr_kernel(
    const float* __restrict__ xin, const int* __restrict__ csr_src,
    const float* __restrict__ csr_w, const int* __restrict__ rowoff,
    float* __restrict__ agg)
{
    const int wave = threadIdx.x >> 6, lane = threadIdx.x & 63;
    const int nbase = (blockIdx.x * 4 + wave) * 8;
    #pragma unroll 2
    for (int rep = 0; rep < 8; ++rep) {
        const int n = nbase + rep;
        const int g = n / NPG, nl = n - g * NPG;
        const size_t gE = (size_t)g * E;
        const int start = rowoff[g * (NPG + 1) + nl];
        const int end   = rowoff[g * (NPG + 1) + nl + 1];
        float acc = 0.f;
        for (int j0 = start; j0 < end; j0 += 64) {
            const int m = end - j0 < 64 ? end - j0 : 64;
            const int idx = j0 + (lane < m ? lane : 0);
            const int ids = csr_src[gE + idx];
            float wch = 1.f;
            if (HASW) wch = csr_w[gE + idx];
            if (KIN == 64) {
                for (int jj = 0; jj < m; ++jj) {
                    const int s = __shfl(ids, jj);
                    if (HASW) {
                        const float w = __shfl(wch, jj);
                        acc = fmaf(w, xin[(size_t)s * KIN + lane], acc);
                    } else {
                        acc += xin[(size_t)s * KIN + lane];
                    }
                }
            } else {  // KIN == 32: two half-waves split the edge list
                const int f = lane & 31, hf = lane >> 5;
                for (int jj = hf; jj < m; jj += 2) {
                    const int s = __shfl(ids, jj);
                    const float w = __shfl(wch, jj);
                    acc = fmaf(w, xin[(size_t)s * KIN + f], acc);
                }
            }
        }
        if (KIN == 32) acc += __shfl_xor(acc, 32);
        if (lane < KIN) agg[(size_t)n * KIN + lane] = acc;
    }
}

// ---------------- fused node linear + relu + pooling score ----------------
// Block = 64 nodes x 4 output-chunks. lane = node, wave = 16-output chunk.
// acc[16] per thread (static indexing, small unroll body -> stays in regs);
// inputs streamed in 8-float chunks; weights wave-uniform -> SGPR operands.
template<int KIN>
__global__ __launch_bounds__(256) void lin_score_kernel(
    const float* __restrict__ agg, const float* __restrict__ xin,
    const float* __restrict__ wr,  const float* __restrict__ br,
    const float* __restrict__ wk,  const float* __restrict__ pw,
    float* __restrict__ h, float* __restrict__ score)
{
    const int lane  = threadIdx.x & 63;
    const int oc    = threadIdx.x >> 6;        // 0..3, wave-uniform
    const int obase = oc * 16;
    const int node  = blockIdx.x * 64 + lane;

    float acc[16];
    #pragma unroll
    for (int o = 0; o < 16; ++o) acc[o] = br[obase + o];

    const float4* ar = (const float4*)(agg + (size_t)node * KIN);
    const float4* xr = (const float4*)(xin + (size_t)node * KIN);
    for (int kb = 0; kb < KIN / 8; ++kb) {
        const float4 a0 = ar[2 * kb], a1 = ar[2 * kb + 1];
        const float4 x0 = xr[2 * kb], x1 = xr[2 * kb + 1];
        const float a[8]  = {a0.x, a0.y, a0.z, a0.w, a1.x, a1.y, a1.z, a1.w};
        const float xv[8] = {x0.x, x0.y, x0.z, x0.w, x1.x, x1.y, x1.z, x1.w};
        #pragma unroll
        for (int o = 0; o < 16; ++o) {
            const float* wro = wr + (size_t)(obase + o) * KIN + kb * 8;
            const float* wko = wk + (size_t)(obase + o) * KIN + kb * 8;
            #pragma unroll
            for (int kk = 0; kk < 8; ++kk) {
                acc[o] = fmaf(a[kk],  wro[kk], acc[o]);
                acc[o] = fmaf(xv[kk], wko[kk], acc[o]);
            }
        }
    }

    float nrm2 = 0.f;
    #pragma unroll
    for (int o = 0; o < 64; ++o) nrm2 = fmaf(pw[o], pw[o], nrm2);

    float p = 0.f;
    #pragma unroll
    for (int o = 0; o < 16; ++o) {
        acc[o] = fmaxf(acc[o], 0.f);
        p = fmaf(acc[o], pw[obase + o], p);
    }
    float4* hrow = (float4*)(h + (size_t)node * 64 + obase);
    #pragma unroll
    for (int q = 0; q < 4; ++q)
        hrow[q] = make_float4(acc[4 * q], acc[4 * q + 1],
                              acc[4 * q + 2], acc[4 * q + 3]);

    __shared__ float pbuf[4][64];
    pbuf[oc][lane] = p;
    __syncthreads();
    if (oc == 0) {
        const float pt = pbuf[0][lane] + pbuf[1][lane] + pbuf[2][lane] + pbuf[3][lane];
        score[node] = tanhf(pt * rsqrtf(nrm2));
    }
}

// ---------------- per-graph top-k via bitonic sort ----------------
// total order: (score desc, index asc) — matches jax.lax.top_k tie-breaking.
template<int NREAL, int KSEL>
__global__ __launch_bounds__(512) void topk_kernel(
    const float* __restrict__ score, int* __restrict__ sel, int* __restrict__ nidx)
{
    __shared__ float sval[1024];
    __shared__ int   sidx[1024];
    const int g = blockIdx.x, tid = threadIdx.x;
    for (int i = tid; i < 1024; i += 512) {
        sval[i] = (i < NREAL) ? score[(size_t)g * NREAL + i] : -2.0f;
        sidx[i] = i;
    }
    __syncthreads();
    for (int k = 2; k <= 1024; k <<= 1)
        for (int j = k >> 1; j > 0; j >>= 1) {
            for (int i = tid; i < 1024; i += 512) {
                const int l = i ^ j;
                if (l > i) {
                    const float a = sval[i], bv = sval[l];
                    const int   ia = sidx[i], ib = sidx[l];
                    const bool swap_desc = (a < bv) || (a == bv && ia > ib);
                    if (swap_desc == ((i & k) == 0)) {
                        sval[i] = bv; sval[l] = a;
                        sidx[i] = ib; sidx[l] = ia;
                    }
                }
            }
            __syncthreads();
        }
    for (int j = tid; j < NREAL; j += 512) {
        const int node = sidx[j];
        if (j < KSEL) {
            sel[(size_t)g * KSEL + j] = node;
            nidx[(size_t)g * NREAL + node] = g * KSEL + j;
        } else {
            nidx[(size_t)g * NREAL + node] = -1;
        }
    }
}

// ---------------- pooled gather: xg[new] = h[old] * score[old] ----------------
__global__ __launch_bounds__(256) void gather_kernel(
    const float* __restrict__ h, const float* __restrict__ score,
    const int* __restrict__ sel, float* __restrict__ xg, int KSEL, int NPREV)
{
    const size_t i = (size_t)blockIdx.x * 256 + threadIdx.x;
    const int f = (int)(i & 63);
    const size_t n = i >> 6;
    const int g = (int)(n / KSEL);
    const int old = sel[n];
    const size_t oldg = (size_t)g * NPREV + old;
    xg[i] = h[oldg * 64 + f] * score[oldg];
}

// ---------------- readout: concat(max, mean) over k nodes ----------------
__global__ __launch_bounds__(256) void readout_kernel(
    const float* __restrict__ xg, float* __restrict__ out, int KSEL)
{
    const int g = blockIdx.x, tid = threadIdx.x;
    const int f = tid & 63, jc = tid >> 6;
    float mx = -3.4e38f, sm = 0.f;
    #pragma unroll 4
    for (int j = jc; j < KSEL; j += 4) {
        const float v = xg[((size_t)g * KSEL + j) * 64 + f];
        mx = fmaxf(mx, v); sm += v;
    }
    __shared__ float smx[256], ssm[256];
    smx[tid] = mx; ssm[tid] = sm;
    __syncthreads();
    if (tid < 64) {
        mx = fmaxf(fmaxf(smx[tid], smx[tid + 64]), fmaxf(smx[tid + 128], smx[tid + 192]));
        sm = ssm[tid] + ssm[tid + 64] + ssm[tid + 128] + ssm[tid + 192];
        out[g * 128 + tid] = mx;
        out[g * 128 + 64 + tid] = sm / (float)KSEL;
    }
}

// ---------------- final MLP + log_softmax (one wave per graph) ----------------
__global__ __launch_bounds__(64) void mlp_kernel(
    const float* __restrict__ x1, const float* __restrict__ x2, const float* __restrict__ x3,
    const float* __restrict__ w1, const float* __restrict__ b1,
    const float* __restrict__ w2, const float* __restrict__ b2,
    const float* __restrict__ w3, const float* __restrict__ b3,
    const float* __restrict__ w4, const float* __restrict__ b4,
    float* __restrict__ out)
{
    const int g = blockIdx.x, lane = threadIdx.x;
    __shared__ float z[128], a1[64], a2[32], a3[16], y[16], red[2];
    z[lane]      = x1[g * 128 + lane]      + x2[g * 128 + lane]      + x3[g * 128 + lane];
    z[lane + 64] = x1[g * 128 + 64 + lane] + x2[g * 128 + 64 + lane] + x3[g * 128 + 64 + lane];
    __syncthreads();
    float acc = b1[lane];
    #pragma unroll
    for (int k = 0; k < 128; ++k) acc = fmaf(z[k], w1[lane * 128 + k], acc);
    a1[lane] = fmaxf(acc, 0.f);
    __syncthreads();
    if (lane < 32) {
        float a = b2[lane];
        #pragma unroll
        for (int k = 0; k < 64; ++k) a = fmaf(a1[k], w2[lane * 64 + k], a);
        a2[lane] = fmaxf(a, 0.f);
    }
    __syncthreads();
    if (lane < 16) {
        float a = b3[lane];
        #pragma unroll
        for (int k = 0; k < 32; ++k) a = fmaf(a2[k], w3[lane * 32 + k], a);
        a3[lane] = fmaxf(a, 0.f);
    }
    __syncthreads();
    if (lane < NCLS) {
        float a = b4[lane];
        #pragma unroll
        for (int k = 0; k < 16; ++k) a = fmaf(a3[k], w4[lane * 16 + k], a);
        y[lane] = a;
    }
    __syncthreads();
    if (lane == 0) {
        float m = y[0];
        for (int c = 1; c < NCLS; ++c) m = fmaxf(m, y[c]);
        float s = 0.f;
        for (int c = 0; c < NCLS; ++c) s += expf(y[c] - m);
        red[0] = m; red[1] = logf(s);
    }
    __syncthreads();
    if (lane < NCLS) out[g * NCLS + lane] = y[lane] - red[0] - red[1];
}

// ---------------- workspace layout (bytes) ----------------
constexpr size_t OFF_H      = 0;                                     // B*N*64 f32
constexpr size_t OFF_AGG    = OFF_H      + (size_t)B * N * H * 4;
constexpr size_t OFF_XG     = OFF_AGG    + (size_t)B * N * H * 4;    // B*K1*64 f32
constexpr size_t OFF_SCORE  = OFF_XG     + (size_t)B * K1 * H * 4;
constexpr size_t OFF_SEL    = OFF_SCORE  + (size_t)B * N * 4;
constexpr size_t OFF_NIDX   = OFF_SEL    + (size_t)B * K1 * 4;
constexpr size_t OFF_CSRS   = OFF_NIDX   + (size_t)B * N * 4;        // B*E int
constexpr size_t OFF_CSRW   = OFF_CSRS   + (size_t)B * E * 4;        // B*E f32 (stage1) / esrc (stages 2,3)
constexpr size_t OFF_EDST   = OFF_CSRW   + (size_t)B * E * 4;        // B*E int
constexpr size_t OFF_ROW    = OFF_EDST   + (size_t)B * E * 4;        // B*(N+1) int
constexpr size_t OFF_X1     = OFF_ROW    + (size_t)B * (N + 1) * 4;
constexpr size_t OFF_X2     = OFF_X1     + (size_t)B * 128 * 4;
constexpr size_t OFF_X3     = OFF_X2     + (size_t)B * 128 * 4;

extern "C" void kernel_launch(void* const* d_in, const int* in_sizes, int n_in,
                              void* d_out, int out_size, void* d_ws, size_t ws_size,
                              hipStream_t stream)
{
    (void)in_sizes; (void)n_in; (void)out_size; (void)ws_size;
    const float* x     = (const float*)d_in[0];
    const int*   eidx  = (const int*)d_in[1];
    const float* eattr = (const float*)d_in[2];
    const int* src0 = eidx;
    const int* dst0 = eidx + (size_t)B * E;
    const float* c1_wr = (const float*)d_in[3],  *c1_br = (const float*)d_in[4];
    const float* c1_wk = (const float*)d_in[5],  *p1_w  = (const float*)d_in[6];
    const float* c2_wr = (const float*)d_in[7],  *c2_br = (const float*)d_in[8];
    const float* c2_wk = (const float*)d_in[9],  *p2_w  = (const float*)d_in[10];
    const float* c3_wr = (const float*)d_in[11], *c3_br = (const float*)d_in[12];
    const float* c3_wk = (const float*)d_in[13], *p3_w  = (const float*)d_in[14];
    const float* l1_w = (const float*)d_in[15], *l1_b = (const float*)d_in[16];
    const float* l2_w = (const float*)d_in[17], *l2_b = (const float*)d_in[18];
    const float* l3_w = (const float*)d_in[19], *l3_b = (const float*)d_in[20];
    const float* l4_w = (const float*)d_in[21], *l4_b = (const float*)d_in[22];

    char* ws = (char*)d_ws;
    float* h       = (float*)(ws + OFF_H);
    float* agg     = (float*)(ws + OFF_AGG);
    float* xg      = (float*)(ws + OFF_XG);
    float* score   = (float*)(ws + OFF_SCORE);
    int*   sel     = (int*)  (ws + OFF_SEL);
    int*   nidx    = (int*)  (ws + OFF_NIDX);
    int*   csr_src = (int*)  (ws + OFF_CSRS);
    float* csr_w   = (float*)(ws + OFF_CSRW);   // stage 1 weights
    int*   esrc    = (int*)  (ws + OFF_CSRW);   // stages 2/3 remapped src (aliases csr_w)
    int*   edst    = (int*)  (ws + OFF_EDST);
    int*   rowoff  = (int*)  (ws + OFF_ROW);
    float* x1      = (float*)(ws + OFF_X1);
    float* x2      = (float*)(ws + OFF_X2);
    float* x3      = (float*)(ws + OFF_X3);
    float* out     = (float*)d_out;

    // ---- stage 1 ----
    build_kernel<N, false, true><<<B, 1024, 0, stream>>>(
        src0, dst0, nullptr, eattr, nullptr, nullptr, rowoff, csr_src, csr_w);
    agg_csr_kernel<FIN, N, true><<<(B * N) / 32, 256, 0, stream>>>(
        x, csr_src, csr_w, rowoff, agg);
    lin_score_kernel<FIN><<<(B * N) / 64, 256, 0, stream>>>(
        agg, x, c1_wr, c1_br, c1_wk, p1_w, h, score);
    topk_kernel<N, K1><<<B, 512, 0, stream>>>(score, sel, nidx);
    gather_kernel<<<(B * K1 * 64) / 256, 256, 0, stream>>>(h, score, sel, xg, K1, N);
    readout_kernel<<<B, 256, 0, stream>>>(xg, x1, K1);

    // ---- stage 2 ----  (remap stage-1 edges through nidx1, build CSR over K1 nodes)
    build_kernel<K1, true, false><<<B, 1024, 0, stream>>>(
        src0, dst0, nidx, nullptr, esrc, edst, rowoff, csr_src, nullptr);
    agg_csr_kernel<H, K1, false><<<(B * K1) / 32, 256, 0, stream>>>(
        xg, csr_src, nullptr, rowoff, agg);
    lin_score_kernel<H><<<(B * K1) / 64, 256, 0, stream>>>(
        agg, xg, c2_wr, c2_br, c2_wk, p2_w, h, score);
    topk_kernel<K1, K2><<<B, 512, 0, stream>>>(score, sel, nidx);
    gather_kernel<<<(B * K2 * 64) / 256, 256, 0, stream>>>(h, score, sel, xg, K2, K1);
    readout_kernel<<<B, 256, 0, stream>>>(xg, x2, K2);

    // ---- stage 3 ----  (remap stage-2 edges in place through nidx2)
    build_kernel<K2, true, false><<<B, 1024, 0, stream>>>(
        esrc, edst, nidx, nullptr, esrc, edst, rowoff, csr_src, nullptr);
    agg_csr_kernel<H, K2, false><<<(B * K2) / 32, 256, 0, stream>>>(
        xg, csr_src, nullptr, rowoff, agg);
    lin_score_kernel<H><<<(B * K2) / 64, 256, 0, stream>>>(
        agg, xg, c3_wr, c3_br, c3_wk, p3_w, h, score);
    topk_kernel<K2, K3><<<B, 512, 0, stream>>>(score, sel, nidx);
    gather_kernel<<<(B * K3 * 64) / 256, 256, 0, stream>>>(h, score, sel, xg, K3, K2);
    readout_kernel<<<B, 256, 0, stream>>>(xg, x3, K3);

    // ---- head ----
    mlp_kernel<<<B, 64, 0, stream>>>(x1, x2, x3, l1_w, l1_b, l2_w, l2_b,
                                     l3_w, l3_b, l4_w, l4_b, out);
}

// Round 12
// 720.848 us; speedup vs baseline: 1.5408x; 1.2894x over previous
//
#include <hip/hip_runtime.h>
#include <math.h>

// ---------------- problem constants ----------------
constexpr int B  = 128;
constexpr int N  = 1024;
constexpr int E  = 16384;
constexpr int FIN = 32;
constexpr int H  = 64;
constexpr int K1 = 820, K2 = 656, K3 = 525;
constexpr int NCLS = 10;

// ---------------- CSR build: histogram + scan + scatter (1 block/graph) ----
template<int NPG, bool REMAP, bool HASW>
__global__ __launch_bounds__(1024) void build_kernel(
    const int* __restrict__ src_in, const int* __restrict__ dst_in,
    const int* __restrict__ nidx,  const float* __restrict__ w_in,
    int* __restrict__ esrc_out, int* __restrict__ edst_out,
    int* __restrict__ rowoff, int* __restrict__ csr_src, float* __restrict__ csr_w)
{
    __shared__ int cnt[1024];
    __shared__ int excl[1024];
    const int g = blockIdx.x, tid = threadIdx.x;
    cnt[tid] = 0;
    __syncthreads();
    const size_t gE = (size_t)g * E;
    int sreg[16], dreg[16];
    #pragma unroll
    for (int i = 0; i < 16; ++i) {
        const int e = tid + i * 1024;
        int s = src_in[gE + e], d = dst_in[gE + e];
        if (REMAP) {
            s = (s >= 0) ? nidx[s] : -1;
            d = (d >= 0) ? nidx[d] : -1;
            esrc_out[gE + e] = s;
            edst_out[gE + e] = d;
        }
        if (s < 0 || d < 0) { s = -1; d = -1; }
        sreg[i] = s; dreg[i] = d;
        if (d >= 0) atomicAdd(&cnt[d - g * NPG], 1);
    }
    __syncthreads();
    const int v = (tid < NPG) ? cnt[tid] : 0;
    excl[tid] = v;
    __syncthreads();
    int run = v;
    for (int dd = 1; dd < 1024; dd <<= 1) {
        const int t = (tid >= dd) ? excl[tid - dd] : 0;
        __syncthreads();
        run += t;
        excl[tid] = run;
        __syncthreads();
    }
    const int ex = run - v;                    // exclusive prefix
    if (tid < NPG) rowoff[(size_t)g * (NPG + 1) + tid] = ex;
    if (tid == NPG - 1) rowoff[(size_t)g * (NPG + 1) + NPG] = run;
    excl[tid] = ex;
    cnt[tid] = 0;
    __syncthreads();
    #pragma unroll
    for (int i = 0; i < 16; ++i) {
        const int d = dreg[i];
        if (d >= 0) {
            const int dl = d - g * NPG;
            const int pos = excl[dl] + atomicAdd(&cnt[dl], 1);
            csr_src[gE + pos] = sreg[i];
            if (HASW) csr_w[gE + pos] = w_in[gE + tid + i * 1024];
        }
    }
}

// ---------------- CSR gather-aggregate ----------------
template<int KIN, int NPG, bool HASW>
__global__ __launch_bounds__(256) void agg_csr_kernel(
    const float* __restrict__ xin, const int* __restrict__ csr_src,
    const float* __restrict__ csr_w, const int* __restrict__ rowoff,
    float* __restrict__ agg)
{
    const int wave = threadIdx.x >> 6, lane = threadIdx.x & 63;
    const int nbase = (blockIdx.x * 4 + wave) * 8;
    #pragma unroll 2
    for (int rep = 0; rep < 8; ++rep) {
        const int n = nbase + rep;
        const int g = n / NPG, nl = n - g * NPG;
        const size_t gE = (size_t)g * E;
        const int start = rowoff[g * (NPG + 1) + nl];
        const int end   = rowoff[g * (NPG + 1) + nl + 1];
        float acc = 0.f;
        for (int j0 = start; j0 < end; j0 += 64) {
            const int m = end - j0 < 64 ? end - j0 : 64;
            const int idx = j0 + (lane < m ? lane : 0);
            const int ids = csr_src[gE + idx];
            float wch = 1.f;
            if (HASW) wch = csr_w[gE + idx];
            if (KIN == 64) {
                for (int jj = 0; jj < m; ++jj) {
                    const int s = __shfl(ids, jj);
                    if (HASW) {
                        const float w = __shfl(wch, jj);
                        acc = fmaf(w, xin[(size_t)s * KIN + lane], acc);
                    } else {
                        acc += xin[(size_t)s * KIN + lane];
                    }
                }
            } else {  // KIN == 32: two half-waves split the edge list
                const int f = lane & 31, hf = lane >> 5;
                for (int jj = hf; jj < m; jj += 2) {
                    const int s = __shfl(ids, jj);
                    const float w = __shfl(wch, jj);
                    acc = fmaf(w, xin[(size_t)s * KIN + f], acc);
                }
            }
        }
        if (KIN == 32) acc += __shfl_xor(acc, 32);
        if (lane < KIN) agg[(size_t)n * KIN + lane] = acc;
    }
}

// ---------------- fused node linear + relu + pooling score ----------------
// Block = 128 nodes x 64 outputs. lane = node (2 nodes/lane), wave = 16 outs.
// Weights staged once to LDS (coalesced vector loads), inner loop reads them
// as 64-lane broadcast ds_read_b128 (conflict-free). 8 FMA per LDS instr.
template<int KIN>
__global__ __launch_bounds__(256, 2) void lin_score_kernel(
    const float* __restrict__ agg, const float* __restrict__ xin,
    const float* __restrict__ wr,  const float* __restrict__ br,
    const float* __restrict__ wk,  const float* __restrict__ pw,
    float* __restrict__ h, float* __restrict__ score)
{
    constexpr int NVF = 64 * KIN;              // floats per weight matrix
    __shared__ float s_w[2 * NVF];             // [wr rows | wk rows]
    __shared__ float pbuf[4][128];
    const int tid = threadIdx.x;
    {
        float4* dst = (float4*)s_w;
        const float4* s1 = (const float4*)wr;
        const float4* s2 = (const float4*)wk;
        #pragma unroll
        for (int i = tid; i < NVF / 4; i += 256) dst[i] = s1[i];
        #pragma unroll
        for (int i = tid; i < NVF / 4; i += 256) dst[NVF / 4 + i] = s2[i];
    }
    __syncthreads();

    const int lane  = tid & 63;
    const int oc    = tid >> 6;                // 0..3
    const int obase = oc * 16;
    const int n0 = blockIdx.x * 128 + lane;
    const int n1 = n0 + 64;

    float acc0[16], acc1[16];
    #pragma unroll
    for (int o = 0; o < 16; ++o) {
        const float b = br[obase + o];
        acc0[o] = b; acc1[o] = b;
    }

    const float4* ar0 = (const float4*)(agg + (size_t)n0 * KIN);
    const float4* xr0 = (const float4*)(xin + (size_t)n0 * KIN);
    const float4* ar1 = (const float4*)(agg + (size_t)n1 * KIN);
    const float4* xr1 = (const float4*)(xin + (size_t)n1 * KIN);

    for (int kb = 0; kb < KIN / 8; ++kb) {
        const float4 a00 = ar0[2 * kb], a01 = ar0[2 * kb + 1];
        const float4 x00 = xr0[2 * kb], x01 = xr0[2 * kb + 1];
        const float4 a10 = ar1[2 * kb], a11 = ar1[2 * kb + 1];
        const float4 x10 = xr1[2 * kb], x11 = xr1[2 * kb + 1];
        const float a0[8] = {a00.x,a00.y,a00.z,a00.w,a01.x,a01.y,a01.z,a01.w};
        const float x0[8] = {x00.x,x00.y,x00.z,x00.w,x01.x,x01.y,x01.z,x01.w};
        const float a1[8] = {a10.x,a10.y,a10.z,a10.w,a11.x,a11.y,a11.z,a11.w};
        const float x1[8] = {x10.x,x10.y,x10.z,x10.w,x11.x,x11.y,x11.z,x11.w};
        #pragma unroll
        for (int o = 0; o < 16; ++o) {
            const float* wro = &s_w[(obase + o) * KIN + kb * 8];
            const float* wko = &s_w[NVF + (obase + o) * KIN + kb * 8];
            #pragma unroll
            for (int kk = 0; kk < 8; ++kk) {
                const float wv = wro[kk];
                acc0[o] = fmaf(a0[kk], wv, acc0[o]);
                acc1[o] = fmaf(a1[kk], wv, acc1[o]);
                const float kv = wko[kk];
                acc0[o] = fmaf(x0[kk], kv, acc0[o]);
                acc1[o] = fmaf(x1[kk], kv, acc1[o]);
            }
        }
    }

    float nrm2 = 0.f;
    #pragma unroll
    for (int o = 0; o < 64; ++o) nrm2 = fmaf(pw[o], pw[o], nrm2);

    float p0 = 0.f, p1 = 0.f;
    #pragma unroll
    for (int o = 0; o < 16; ++o) {
        const float pwo = pw[obase + o];
        acc0[o] = fmaxf(acc0[o], 0.f);
        acc1[o] = fmaxf(acc1[o], 0.f);
        p0 = fmaf(acc0[o], pwo, p0);
        p1 = fmaf(acc1[o], pwo, p1);
    }
    float4* h0 = (float4*)(h + (size_t)n0 * 64 + obase);
    float4* h1 = (float4*)(h + (size_t)n1 * 64 + obase);
    #pragma unroll
    for (int q = 0; q < 4; ++q) {
        h0[q] = make_float4(acc0[4*q], acc0[4*q+1], acc0[4*q+2], acc0[4*q+3]);
        h1[q] = make_float4(acc1[4*q], acc1[4*q+1], acc1[4*q+2], acc1[4*q+3]);
    }

    pbuf[oc][lane]      = p0;
    pbuf[oc][lane + 64] = p1;
    __syncthreads();
    if (oc == 0) {
        const float inv_norm = rsqrtf(nrm2);
        const float pt0 = pbuf[0][lane] + pbuf[1][lane] + pbuf[2][lane] + pbuf[3][lane];
        const float pt1 = pbuf[0][lane+64] + pbuf[1][lane+64] + pbuf[2][lane+64] + pbuf[3][lane+64];
        score[n0] = tanhf(pt0 * inv_norm);
        score[n1] = tanhf(pt1 * inv_norm);
    }
}

// ---------------- per-graph top-k via bitonic sort ----------------
// total order: (score desc, index asc) — matches jax.lax.top_k tie-breaking.
template<int NREAL, int KSEL>
__global__ __launch_bounds__(512) void topk_kernel(
    const float* __restrict__ score, int* __restrict__ sel, int* __restrict__ nidx)
{
    __shared__ float sval[1024];
    __shared__ int   sidx[1024];
    const int g = blockIdx.x, tid = threadIdx.x;
    for (int i = tid; i < 1024; i += 512) {
        sval[i] = (i < NREAL) ? score[(size_t)g * NREAL + i] : -2.0f;
        sidx[i] = i;
    }
    __syncthreads();
    for (int k = 2; k <= 1024; k <<= 1)
        for (int j = k >> 1; j > 0; j >>= 1) {
            for (int i = tid; i < 1024; i += 512) {
                const int l = i ^ j;
                if (l > i) {
                    const float a = sval[i], bv = sval[l];
                    const int   ia = sidx[i], ib = sidx[l];
                    const bool swap_desc = (a < bv) || (a == bv && ia > ib);
                    if (swap_desc == ((i & k) == 0)) {
                        sval[i] = bv; sval[l] = a;
                        sidx[i] = ib; sidx[l] = ia;
                    }
                }
            }
            __syncthreads();
        }
    for (int j = tid; j < NREAL; j += 512) {
        const int node = sidx[j];
        if (j < KSEL) {
            sel[(size_t)g * KSEL + j] = node;
            nidx[(size_t)g * NREAL + node] = g * KSEL + j;
        } else {
            nidx[(size_t)g * NREAL + node] = -1;
        }
    }
}

// ---------------- pooled gather: xg[new] = h[old] * score[old] ----------------
__global__ __launch_bounds__(256) void gather_kernel(
    const float* __restrict__ h, const float* __restrict__ score,
    const int* __restrict__ sel, float* __restrict__ xg, int KSEL, int NPREV)
{
    const size_t i = (size_t)blockIdx.x * 256 + threadIdx.x;
    const int f = (int)(i & 63);
    const size_t n = i >> 6;
    const int g = (int)(n / KSEL);
    const int old = sel[n];
    const size_t oldg = (size_t)g * NPREV + old;
    xg[i] = h[oldg * 64 + f] * score[oldg];
}

// ---------------- readout: concat(max, mean) over k nodes ----------------
__global__ __launch_bounds__(256) void readout_kernel(
    const float* __restrict__ xg, float* __restrict__ out, int KSEL)
{
    const int g = blockIdx.x, tid = threadIdx.x;
    const int f = tid & 63, jc = tid >> 6;
    float mx = -3.4e38f, sm = 0.f;
    #pragma unroll 4
    for (int j = jc; j < KSEL; j += 4) {
        const float v = xg[((size_t)g * KSEL + j) * 64 + f];
        mx = fmaxf(mx, v); sm += v;
    }
    __shared__ float smx[256], ssm[256];
    smx[tid] = mx; ssm[tid] = sm;
    __syncthreads();
    if (tid < 64) {
        mx = fmaxf(fmaxf(smx[tid], smx[tid + 64]), fmaxf(smx[tid + 128], smx[tid + 192]));
        sm = ssm[tid] + ssm[tid + 64] + ssm[tid + 128] + ssm[tid + 192];
        out[g * 128 + tid] = mx;
        out[g * 128 + 64 + tid] = sm / (float)KSEL;
    }
}

// ---------------- final MLP + log_softmax (one wave per graph) ----------------
__global__ __launch_bounds__(64) void mlp_kernel(
    const float* __restrict__ x1, const float* __restrict__ x2, const float* __restrict__ x3,
    const float* __restrict__ w1, const float* __restrict__ b1,
    const float* __restrict__ w2, const float* __restrict__ b2,
    const float* __restrict__ w3, const float* __restrict__ b3,
    const float* __restrict__ w4, const float* __restrict__ b4,
    float* __restrict__ out)
{
    const int g = blockIdx.x, lane = threadIdx.x;
    __shared__ float z[128], a1[64], a2[32], a3[16], y[16], red[2];
    z[lane]      = x1[g * 128 + lane]      + x2[g * 128 + lane]      + x3[g * 128 + lane];
    z[lane + 64] = x1[g * 128 + 64 + lane] + x2[g * 128 + 64 + lane] + x3[g * 128 + 64 + lane];
    __syncthreads();
    float acc = b1[lane];
    #pragma unroll
    for (int k = 0; k < 128; ++k) acc = fmaf(z[k], w1[lane * 128 + k], acc);
    a1[lane] = fmaxf(acc, 0.f);
    __syncthreads();
    if (lane < 32) {
        float a = b2[lane];
        #pragma unroll
        for (int k = 0; k < 64; ++k) a = fmaf(a1[k], w2[lane * 64 + k], a);
        a2[lane] = fmaxf(a, 0.f);
    }
    __syncthreads();
    if (lane < 16) {
        float a = b3[lane];
        #pragma unroll
        for (int k = 0; k < 32; ++k) a = fmaf(a2[k], w3[lane * 32 + k], a);
        a3[lane] = fmaxf(a, 0.f);
    }
    __syncthreads();
    if (lane < NCLS) {
        float a = b4[lane];
        #pragma unroll
        for (int k = 0; k < 16; ++k) a = fmaf(a3[k], w4[lane * 16 + k], a);
        y[lane] = a;
    }
    __syncthreads();
    if (lane == 0) {
        float m = y[0];
        for (int c = 1; c < NCLS; ++c) m = fmaxf(m, y[c]);
        float s = 0.f;
        for (int c = 0; c < NCLS; ++c) s += expf(y[c] - m);
        red[0] = m; red[1] = logf(s);
    }
    __syncthreads();
    if (lane < NCLS) out[g * NCLS + lane] = y[lane] - red[0] - red[1];
}

// ---------------- workspace layout (bytes) ----------------
constexpr size_t OFF_H      = 0;                                     // B*N*64 f32
constexpr size_t OFF_AGG    = OFF_H      + (size_t)B * N * H * 4;
constexpr size_t OFF_XG     = OFF_AGG    + (size_t)B * N * H * 4;    // B*K1*64 f32
constexpr size_t OFF_SCORE  = OFF_XG     + (size_t)B * K1 * H * 4;
constexpr size_t OFF_SEL    = OFF_SCORE  + (size_t)B * N * 4;
constexpr size_t OFF_NIDX   = OFF_SEL    + (size_t)B * K1 * 4;
constexpr size_t OFF_CSRS   = OFF_NIDX   + (size_t)B * N * 4;        // B*E int
constexpr size_t OFF_CSRW   = OFF_CSRS   + (size_t)B * E * 4;        // B*E f32 (stage1) / esrc (stages 2,3)
constexpr size_t OFF_EDST   = OFF_CSRW   + (size_t)B * E * 4;        // B*E int
constexpr size_t OFF_ROW    = OFF_EDST   + (size_t)B * E * 4;        // B*(N+1) int
constexpr size_t OFF_X1     = OFF_ROW    + (size_t)B * (N + 1) * 4;
constexpr size_t OFF_X2     = OFF_X1     + (size_t)B * 128 * 4;
constexpr size_t OFF_X3     = OFF_X2     + (size_t)B * 128 * 4;

extern "C" void kernel_launch(void* const* d_in, const int* in_sizes, int n_in,
                              void* d_out, int out_size, void* d_ws, size_t ws_size,
                              hipStream_t stream)
{
    (void)in_sizes; (void)n_in; (void)out_size; (void)ws_size;
    const float* x     = (const float*)d_in[0];
    const int*   eidx  = (const int*)d_in[1];
    const float* eattr = (const float*)d_in[2];
    const int* src0 = eidx;
    const int* dst0 = eidx + (size_t)B * E;
    const float* c1_wr = (const float*)d_in[3],  *c1_br = (const float*)d_in[4];
    const float* c1_wk = (const float*)d_in[5],  *p1_w  = (const float*)d_in[6];
    const float* c2_wr = (const float*)d_in[7],  *c2_br = (const float*)d_in[8];
    const float* c2_wk = (const float*)d_in[9],  *p2_w  = (const float*)d_in[10];
    const float* c3_wr = (const float*)d_in[11], *c3_br = (const float*)d_in[12];
    const float* c3_wk = (const float*)d_in[13], *p3_w  = (const float*)d_in[14];
    const float* l1_w = (const float*)d_in[15], *l1_b = (const float*)d_in[16];
    const float* l2_w = (const float*)d_in[17], *l2_b = (const float*)d_in[18];
    const float* l3_w = (const float*)d_in[19], *l3_b = (const float*)d_in[20];
    const float* l4_w = (const float*)d_in[21], *l4_b = (const float*)d_in[22];

    char* ws = (char*)d_ws;
    float* h       = (float*)(ws + OFF_H);
    float* agg     = (float*)(ws + OFF_AGG);
    float* xg      = (float*)(ws + OFF_XG);
    float* score   = (float*)(ws + OFF_SCORE);
    int*   sel     = (int*)  (ws + OFF_SEL);
    int*   nidx    = (int*)  (ws + OFF_NIDX);
    int*   csr_src = (int*)  (ws + OFF_CSRS);
    float* csr_w   = (float*)(ws + OFF_CSRW);   // stage 1 weights
    int*   esrc    = (int*)  (ws + OFF_CSRW);   // stages 2/3 remapped src (aliases csr_w)
    int*   edst    = (int*)  (ws + OFF_EDST);
    int*   rowoff  = (int*)  (ws + OFF_ROW);
    float* x1      = (float*)(ws + OFF_X1);
    float* x2      = (float*)(ws + OFF_X2);
    float* x3      = (float*)(ws + OFF_X3);
    float* out     = (float*)d_out;

    // ---- stage 1 ----
    build_kernel<N, false, true><<<B, 1024, 0, stream>>>(
        src0, dst0, nullptr, eattr, nullptr, nullptr, rowoff, csr_src, csr_w);
    agg_csr_kernel<FIN, N, true><<<(B * N) / 32, 256, 0, stream>>>(
        x, csr_src, csr_w, rowoff, agg);
    lin_score_kernel<FIN><<<(B * N) / 128, 256, 0, stream>>>(
        agg, x, c1_wr, c1_br, c1_wk, p1_w, h, score);
    topk_kernel<N, K1><<<B, 512, 0, stream>>>(score, sel, nidx);
    gather_kernel<<<(B * K1 * 64) / 256, 256, 0, stream>>>(h, score, sel, xg, K1, N);
    readout_kernel<<<B, 256, 0, stream>>>(xg, x1, K1);

    // ---- stage 2 ----  (remap stage-1 edges through nidx1, build CSR over K1 nodes)
    build_kernel<K1, true, false><<<B, 1024, 0, stream>>>(
        src0, dst0, nidx, nullptr, esrc, edst, rowoff, csr_src, nullptr);
    agg_csr_kernel<H, K1, false><<<(B * K1) / 32, 256, 0, stream>>>(
        xg, csr_src, nullptr, rowoff, agg);
    lin_score_kernel<H><<<(B * K1) / 128, 256, 0, stream>>>(
        agg, xg, c2_wr, c2_br, c2_wk, p2_w, h, score);
    topk_kernel<K1, K2><<<B, 512, 0, stream>>>(score, sel, nidx);
    gather_kernel<<<(B * K2 * 64) / 256, 256, 0, stream>>>(h, score, sel, xg, K2, K1);
    readout_kernel<<<B, 256, 0, stream>>>(xg, x2, K2);

    // ---- stage 3 ----  (remap stage-2 edges in place through nidx2)
    build_kernel<K2, true, false><<<B, 1024, 0, stream>>>(
        esrc, edst, nidx, nullptr, esrc, edst, rowoff, csr_src, nullptr);
    agg_csr_kernel<H, K2, false><<<(B * K2) / 32, 256, 0, stream>>>(
        xg, csr_src, nullptr, rowoff, agg);
    lin_score_kernel<H><<<(B * K2) / 128, 256, 0, stream>>>(
        agg, xg, c3_wr, c3_br, c3_wk, p3_w, h, score);
    topk_kernel<K2, K3><<<B, 512, 0, stream>>>(score, sel, nidx);
    gather_kernel<<<(B * K3 * 64) / 256, 256, 0, stream>>>(h, score, sel, xg, K3, K2);
    readout_kernel<<<B, 256, 0, stream>>>(xg, x3, K3);

    // ---- head ----
    mlp_kernel<<<B, 64, 0, stream>>>(x1, x2, x3, l1_w, l1_b, l2_w, l2_b,
                                     l3_w, l3_b, l4_w, l4_b, out);
}